// Round 1
// baseline (1053.811 us; speedup 1.0000x reference)
//
#include <hip/hip_runtime.h>
#include <hip/hip_bf16.h>

typedef __bf16 bf16_t;
typedef __bf16 bf16x4 __attribute__((ext_vector_type(4)));
typedef __bf16 bf16x8 __attribute__((ext_vector_type(8)));
typedef float f32x4 __attribute__((ext_vector_type(4)));

#define B_ 32
#define N_ 16384
#define C_ 256
#define D_ 64
#define ROWS_TOTAL (B_ * N_)  // 524288

__device__ inline float wave_sum64(float v) {
#pragma unroll
  for (int o = 1; o < 64; o <<= 1) v += __shfl_xor(v, o);
  return v;
}

__device__ inline float sigmoidf_(float x) { return 1.0f / (1.0f + __expf(-x)); }
__device__ inline float tanhf_(float x) { return 1.0f - 2.0f / (__expf(2.0f * x) + 1.0f); }

// ---------------------------------------------------------------------------
// prep: Wb = [Wk|Wv] (256x128) in MFMA B-frag layout (bf16); transpose GRU
// weights for coalesced reads; init g from slots_mu.
// grid: 280 x 256 covers 71680 tasks exactly.
// ---------------------------------------------------------------------------
__global__ __launch_bounds__(256) void prep_kernel(
    const float* __restrict__ Wk, const float* __restrict__ Wv,
    const float* __restrict__ Wih, const float* __restrict__ Whh,
    const float* __restrict__ slots, bf16_t* __restrict__ Wb,
    float* __restrict__ WihT, float* __restrict__ WhhT, float* __restrict__ g) {
  int i = blockIdx.x * 256 + threadIdx.x;
  if (i < 32768) {
    // i = ((kb*8 + t)*64 + l)*8 + j ; frag elem = W[k][n], n=l&15, k=(l>>4)*8+j
    int j = i & 7, l = (i >> 3) & 63, t = (i >> 9) & 7, kb = i >> 12;
    int k = kb * 32 + (l >> 4) * 8 + j;
    int n = t * 16 + (l & 15);
    float v = (n < 64) ? Wk[k * 64 + n] : Wv[k * 64 + (n - 64)];
    Wb[i] = (bf16_t)v;
  } else if (i < 45056) {
    int idx = i - 32768;
    int c = idx / 192, j = idx % 192;
    WihT[idx] = Wih[j * 64 + c];
  } else if (i < 57344) {
    int idx = i - 45056;
    int c = idx / 192, j = idx % 192;
    WhhT[idx] = Whh[j * 64 + c];
  } else if (i < 71680) {
    int idx = i - 57344;
    g[idx] = slots[idx];
  }
}

// ---------------------------------------------------------------------------
// proj_ln: fused LN(inputs) -> bf16 x-tile in LDS -> MFMA -> k,v (bf16).
// block = 256 thr (4 waves), tile = 128 rows. LDS x-tile XOR-swizzled:
// element (r,c) lives at unit = r*32 + ((c>>3) ^ (r&31)), 16B units.
// grid: 4096 blocks.
// ---------------------------------------------------------------------------
__global__ __launch_bounds__(256) void proj_ln_kernel(
    const float* __restrict__ inp, const float* __restrict__ lng,
    const float* __restrict__ lnb, const bf16_t* __restrict__ Wb,
    bf16_t* __restrict__ kbuf, bf16_t* __restrict__ vbuf) {
  __shared__ bf16_t xs[128 * 256];  // 64 KB, swizzled
  const int tid = threadIdx.x, w = tid >> 6, lane = tid & 63;
  const int q4 = lane >> 4, lp = lane & 15;
  const long row0 = (long)blockIdx.x * 128;

  float4 gv = *(const float4*)(lng + lane * 4);
  float4 bv = *(const float4*)(lnb + lane * 4);

  // Phase 1: LN, one row per wave-iteration (wave w owns rows w*32..w*32+31)
  for (int i = 0; i < 32; ++i) {
    int r = w * 32 + i;
    float4 x = *(const float4*)(inp + (row0 + r) * C_ + lane * 4);
    float s = x.x + x.y + x.z + x.w;
    float s2 = x.x * x.x + x.y * x.y + x.z * x.z + x.w * x.w;
#pragma unroll
    for (int o = 1; o < 64; o <<= 1) {
      s += __shfl_xor(s, o);
      s2 += __shfl_xor(s2, o);
    }
    float mean = s * (1.0f / 256.0f);
    float var = s2 * (1.0f / 256.0f) - mean * mean;
    float rstd = rsqrtf(var + 1e-5f);
    bf16x4 y;
    y[0] = (bf16_t)((x.x - mean) * rstd * gv.x + bv.x);
    y[1] = (bf16_t)((x.y - mean) * rstd * gv.y + bv.y);
    y[2] = (bf16_t)((x.z - mean) * rstd * gv.z + bv.z);
    y[3] = (bf16_t)((x.w - mean) * rstd * gv.w + bv.w);
    // c = lane*4 -> c_idx = lane>>1, half = lane&1
    size_t unit = (size_t)(r * 32 + ((lane >> 1) ^ (r & 31)));
    *(bf16x4*)(xs + unit * 8 + (lane & 1) * 4) = y;
  }
  __syncthreads();

  // Phase 2: GEMM. wave w -> rows w*32..w*32+31 (2 m-tiles of 16)
  f32x4 acc[2][8];
  const f32x4 zf = {0.0f, 0.0f, 0.0f, 0.0f};
#pragma unroll
  for (int mt = 0; mt < 2; ++mt)
#pragma unroll
    for (int t = 0; t < 8; ++t) acc[mt][t] = zf;

  for (int kb = 0; kb < 8; ++kb) {
    int cidx = kb * 4 + q4;  // c0 = kb*32 + q4*8, c0>>3
    int r0 = w * 32 + lp;
    int r1 = r0 + 16;
    bf16x8 a0 = *(const bf16x8*)(xs + (size_t)(r0 * 32 + (cidx ^ (r0 & 31))) * 8);
    bf16x8 a1 = *(const bf16x8*)(xs + (size_t)(r1 * 32 + (cidx ^ (r1 & 31))) * 8);
#pragma unroll
    for (int t = 0; t < 8; ++t) {
      bf16x8 bf = *(const bf16x8*)(Wb + (size_t)((kb * 8 + t) * 64 + lane) * 8);
      acc[0][t] = __builtin_amdgcn_mfma_f32_16x16x32_bf16(a0, bf, acc[0][t], 0, 0, 0);
      acc[1][t] = __builtin_amdgcn_mfma_f32_16x16x32_bf16(a1, bf, acc[1][t], 0, 0, 0);
    }
  }

  // Epilogue: D mapping col = lane&15, row = (lane>>4)*4 + reg
#pragma unroll
  for (int mt = 0; mt < 2; ++mt) {
#pragma unroll
    for (int t = 0; t < 8; ++t) {
      bf16_t* dst = (t < 4) ? kbuf : vbuf;
      int c = (t & 3) * 16 + lp;
#pragma unroll
      for (int reg = 0; reg < 4; ++reg) {
        long gr = row0 + w * 32 + mt * 16 + q4 * 4 + reg;
        dst[gr * 64 + c] = (bf16_t)acc[mt][t][reg];
      }
    }
  }
}

// ---------------------------------------------------------------------------
// qk: q[b,m] = LN(g[b,m]) @ (m<6 ? Wq : bWq); also zero acc/wsum for the
// upcoming attend pass. grid 224 x 64.
// ---------------------------------------------------------------------------
__global__ __launch_bounds__(64) void qk_kernel(
    const float* __restrict__ g, const float* __restrict__ qg,
    const float* __restrict__ qb, const float* __restrict__ Wq,
    const float* __restrict__ bqg, const float* __restrict__ bqb,
    const float* __restrict__ bWq, float* __restrict__ q,
    float* __restrict__ acc, float* __restrict__ wsum) {
  __shared__ float sx[64];
  int bid = blockIdx.x, lane = threadIdx.x;
  int m = bid % 7;
  const float* lng = (m < 6) ? qg : bqg;
  const float* lnb = (m < 6) ? qb : bqb;
  const float* W = (m < 6) ? Wq : bWq;
  float gv = g[bid * 64 + lane];
  float s = wave_sum64(gv);
  float s2 = wave_sum64(gv * gv);
  float mean = s * (1.0f / 64.0f);
  float var = s2 * (1.0f / 64.0f) - mean * mean;
  float rstd = rsqrtf(var + 1e-5f);
  sx[lane] = (gv - mean) * rstd * lng[lane] + lnb[lane];
  __syncthreads();
  float qd = 0.0f;
#pragma unroll 8
  for (int c = 0; c < 64; ++c) qd += sx[c] * W[c * 64 + lane];
  q[bid * 64 + lane] = qd;
  acc[bid * 64 + lane] = 0.0f;
  if (lane == 0) wsum[bid] = 0.0f;
}

// ---------------------------------------------------------------------------
// attend: per row n: logits (7) -> softmax + EPS -> accumulate attn*v and attn
// into (B,7,64) acc and (B,7) wsum. 4 rows per wave (16-lane groups).
// grid 1024 x 256, 512 rows per block (one b per block).
// ---------------------------------------------------------------------------
__global__ __launch_bounds__(256) void attend_kernel(
    const bf16_t* __restrict__ kbuf, const bf16_t* __restrict__ vbuf,
    const float* __restrict__ q, float* __restrict__ acc,
    float* __restrict__ wsum) {
  __shared__ float qs[448];
  __shared__ float s_acc[448];
  __shared__ float s_w[7];
  int tid = threadIdx.x, w = tid >> 6, lane = tid & 63;
  int g4 = lane >> 4, lp = lane & 15;
  long chunk0 = (long)blockIdx.x * 512;
  int b = (int)(chunk0 >> 14);

  for (int idx = tid; idx < 448; idx += 256) {
    qs[idx] = q[b * 448 + idx];
    s_acc[idx] = 0.0f;
  }
  if (tid < 7) s_w[tid] = 0.0f;
  __syncthreads();

  float av[7][4];
  float wa[7];
#pragma unroll
  for (int m = 0; m < 7; ++m) {
    wa[m] = 0.0f;
#pragma unroll
    for (int j = 0; j < 4; ++j) av[m][j] = 0.0f;
  }

  const float4* qs4 = (const float4*)qs;
  for (int it = 0; it < 32; ++it) {
    long row = chunk0 + it * 16 + w * 4 + g4;
    bf16x4 kv = *(const bf16x4*)(kbuf + row * 64 + lp * 4);
    bf16x4 vv = *(const bf16x4*)(vbuf + row * 64 + lp * 4);
    float k0 = kv[0], k1 = kv[1], k2 = kv[2], k3 = kv[3];
    float lg[7];
#pragma unroll
    for (int m = 0; m < 7; ++m) {
      float4 qv = qs4[m * 16 + lp];
      lg[m] = k0 * qv.x + k1 * qv.y + k2 * qv.z + k3 * qv.w;
    }
#pragma unroll
    for (int m = 0; m < 7; ++m) {
      lg[m] += __shfl_xor(lg[m], 1);
      lg[m] += __shfl_xor(lg[m], 2);
      lg[m] += __shfl_xor(lg[m], 4);
      lg[m] += __shfl_xor(lg[m], 8);
    }
    float mx = -1e30f;
#pragma unroll
    for (int m = 0; m < 7; ++m) {
      lg[m] *= 0.125f;  // SCALE = D^-0.5
      mx = fmaxf(mx, lg[m]);
    }
    float e[7], s = 0.0f;
#pragma unroll
    for (int m = 0; m < 7; ++m) {
      e[m] = __expf(lg[m] - mx);
      s += e[m];
    }
    float inv = 1.0f / s;
    float v0 = vv[0], v1 = vv[1], v2 = vv[2], v3 = vv[3];
#pragma unroll
    for (int m = 0; m < 7; ++m) {
      float a = e[m] * inv + 1e-6f;
      wa[m] += a;
      av[m][0] += a * v0;
      av[m][1] += a * v1;
      av[m][2] += a * v2;
      av[m][3] += a * v3;
    }
  }

  // reduce across the 4 16-lane groups of the wave
#pragma unroll
  for (int m = 0; m < 7; ++m) {
#pragma unroll
    for (int j = 0; j < 4; ++j) {
      av[m][j] += __shfl_xor(av[m][j], 16);
      av[m][j] += __shfl_xor(av[m][j], 32);
    }
    wa[m] += __shfl_xor(wa[m], 16);
    wa[m] += __shfl_xor(wa[m], 32);
  }
  if (g4 == 0) {
#pragma unroll
    for (int m = 0; m < 7; ++m)
#pragma unroll
      for (int j = 0; j < 4; ++j) atomicAdd(&s_acc[m * 64 + lp * 4 + j], av[m][j]);
  }
  if (lane == 0) {
#pragma unroll
    for (int m = 0; m < 7; ++m) atomicAdd(&s_w[m], wa[m]);
  }
  __syncthreads();
  for (int idx = tid; idx < 448; idx += 256) atomicAdd(&acc[b * 448 + idx], s_acc[idx]);
  if (tid < 7) atomicAdd(&wsum[b * 7 + tid], s_w[tid]);
}

// ---------------------------------------------------------------------------
// update: fu = acc/wsum -> GRU(fu, g) -> +MLP residual -> gout.
// grid 224 x 192.
// ---------------------------------------------------------------------------
__global__ __launch_bounds__(192) void update_kernel(
    const float* __restrict__ acc, const float* __restrict__ wsum,
    const float* __restrict__ g, const float* __restrict__ WihT,
    const float* __restrict__ WhhT, const float* __restrict__ bih,
    const float* __restrict__ bhh, const float* __restrict__ mlg,
    const float* __restrict__ mlb, const float* __restrict__ mW1,
    const float* __restrict__ mb1, const float* __restrict__ mW2,
    const float* __restrict__ mb2, const float* __restrict__ bmlg,
    const float* __restrict__ bmlb, const float* __restrict__ bW1,
    const float* __restrict__ bb1, const float* __restrict__ bW2,
    const float* __restrict__ bb2, float* __restrict__ gout) {
  __shared__ float fu[64], hp[64], gi[192], gh[192], h2[64], xb[64], a1[128];
  int tid = threadIdx.x, bid = blockIdx.x, m = bid % 7;

  const float* lg_;
  const float* lb_;
  const float* W1_;
  const float* b1_;
  const float* W2_;
  const float* b2_;
  if (m < 6) { lg_ = mlg; lb_ = mlb; W1_ = mW1; b1_ = mb1; W2_ = mW2; b2_ = mb2; }
  else       { lg_ = bmlg; lb_ = bmlb; W1_ = bW1; b1_ = bb1; W2_ = bW2; b2_ = bb2; }

  if (tid < 64) {
    float wv = wsum[bid];
    fu[tid] = acc[bid * 64 + tid] / wv;
    hp[tid] = g[bid * 64 + tid];
  }
  __syncthreads();

  {
    int j = tid;  // 0..191
    float a = bih[j], bsum = bhh[j];
    for (int c = 0; c < 64; ++c) {
      a += fu[c] * WihT[c * 192 + j];
      bsum += hp[c] * WhhT[c * 192 + j];
    }
    gi[j] = a;
    gh[j] = bsum;
  }
  __syncthreads();

  if (tid < 64) {
    int d = tid;
    float r = sigmoidf_(gi[d] + gh[d]);
    float z = sigmoidf_(gi[64 + d] + gh[64 + d]);
    float n = tanhf_(gi[128 + d] + r * gh[128 + d]);
    float h = (1.0f - z) * n + z * hp[d];
    h2[d] = h;
    float s = wave_sum64(h);
    float s2 = wave_sum64(h * h);
    float mean = s * (1.0f / 64.0f);
    float var = s2 * (1.0f / 64.0f) - mean * mean;
    xb[d] = (h - mean) * rsqrtf(var + 1e-5f) * lg_[d] + lb_[d];
  }
  __syncthreads();

  if (tid < 128) {
    int hh = tid;
    float a = b1_[hh];
    for (int c = 0; c < 64; ++c) a += xb[c] * W1_[c * 128 + hh];
    a1[hh] = fmaxf(a, 0.0f);
  }
  __syncthreads();

  if (tid < 64) {
    int d = tid;
    float o = b2_[d];
    for (int hh = 0; hh < 128; ++hh) o += a1[hh] * W2_[hh * 64 + d];
    gout[bid * 64 + d] = h2[d] + o;
  }
}

// ---------------------------------------------------------------------------
extern "C" void kernel_launch(void* const* d_in, const int* in_sizes, int n_in,
                              void* d_out, int out_size, void* d_ws, size_t ws_size,
                              hipStream_t stream) {
  const float* inputs   = (const float*)d_in[0];
  const float* slots_mu = (const float*)d_in[1];
  const float* ln_in_g  = (const float*)d_in[2];
  const float* ln_in_b  = (const float*)d_in[3];
  const float* Wk       = (const float*)d_in[4];
  const float* Wv       = (const float*)d_in[5];
  const float* q_ln_g   = (const float*)d_in[6];
  const float* q_ln_b   = (const float*)d_in[7];
  const float* Wq       = (const float*)d_in[8];
  const float* bq_ln_g  = (const float*)d_in[9];
  const float* bq_ln_b  = (const float*)d_in[10];
  const float* bWq      = (const float*)d_in[11];
  const float* gru_Wih  = (const float*)d_in[12];
  const float* gru_Whh  = (const float*)d_in[13];
  const float* gru_bih  = (const float*)d_in[14];
  const float* gru_bhh  = (const float*)d_in[15];
  const float* mlp_ln_g = (const float*)d_in[16];
  const float* mlp_ln_b = (const float*)d_in[17];
  const float* mlp_W1   = (const float*)d_in[18];
  const float* mlp_b1   = (const float*)d_in[19];
  const float* mlp_W2   = (const float*)d_in[20];
  const float* mlp_b2   = (const float*)d_in[21];
  const float* bmlp_ln_g = (const float*)d_in[22];
  const float* bmlp_ln_b = (const float*)d_in[23];
  const float* bmlp_W1  = (const float*)d_in[24];
  const float* bmlp_b1  = (const float*)d_in[25];
  const float* bmlp_W2  = (const float*)d_in[26];
  const float* bmlp_b2  = (const float*)d_in[27];
  float* out = (float*)d_out;

  char* ws = (char*)d_ws;
  const size_t KV_BYTES = (size_t)ROWS_TOTAL * 64 * 2;  // 67108864
  bf16_t* kbuf = (bf16_t*)ws;
  bf16_t* vbuf = (bf16_t*)(ws + KV_BYTES);
  bf16_t* Wb   = (bf16_t*)(ws + 2 * KV_BYTES);
  float* WihT  = (float*)(ws + 2 * KV_BYTES + 65536);
  float* WhhT  = (float*)(ws + 2 * KV_BYTES + 65536 + 49152);
  float* gbuf  = (float*)(ws + 2 * KV_BYTES + 65536 + 2 * 49152);
  float* qbuf  = (float*)(ws + 2 * KV_BYTES + 65536 + 2 * 49152 + 57344);
  float* accb  = (float*)(ws + 2 * KV_BYTES + 65536 + 2 * 49152 + 2 * 57344);
  float* wsumb = (float*)(ws + 2 * KV_BYTES + 65536 + 2 * 49152 + 3 * 57344);

  prep_kernel<<<280, 256, 0, stream>>>(Wk, Wv, gru_Wih, gru_Whh, slots_mu, Wb,
                                       WihT, WhhT, gbuf);
  proj_ln_kernel<<<ROWS_TOTAL / 128, 256, 0, stream>>>(inputs, ln_in_g, ln_in_b,
                                                       Wb, kbuf, vbuf);
  for (int it = 0; it < 3; ++it) {
    qk_kernel<<<224, 64, 0, stream>>>(gbuf, q_ln_g, q_ln_b, Wq, bq_ln_g, bq_ln_b,
                                      bWq, qbuf, accb, wsumb);
    attend_kernel<<<ROWS_TOTAL / 512, 256, 0, stream>>>(kbuf, vbuf, qbuf, accb,
                                                        wsumb);
    update_kernel<<<224, 192, 0, stream>>>(
        accb, wsumb, gbuf, WihT, WhhT, gru_bih, gru_bhh, mlp_ln_g, mlp_ln_b,
        mlp_W1, mlp_b1, mlp_W2, mlp_b2, bmlp_ln_g, bmlp_ln_b, bmlp_W1, bmlp_b1,
        bmlp_W2, bmlp_b2, (it == 2) ? out : gbuf);
  }
}

// Round 2
// 1035.539 us; speedup vs baseline: 1.0176x; 1.0176x over previous
//
#include <hip/hip_runtime.h>
#include <hip/hip_bf16.h>

typedef __bf16 bf16_t;
typedef __bf16 bf16x4 __attribute__((ext_vector_type(4)));
typedef __bf16 bf16x8 __attribute__((ext_vector_type(8)));
typedef float f32x4 __attribute__((ext_vector_type(4)));

#define B_ 32
#define N_ 16384
#define C_ 256
#define D_ 64
#define ROWS_TOTAL (B_ * N_)  // 524288

__device__ inline float wave_sum64(float v) {
#pragma unroll
  for (int o = 1; o < 64; o <<= 1) v += __shfl_xor(v, o);
  return v;
}

__device__ inline float sigmoidf_(float x) { return 1.0f / (1.0f + __expf(-x)); }
__device__ inline float tanhf_(float x) { return 1.0f - 2.0f / (__expf(2.0f * x) + 1.0f); }

// ---------------------------------------------------------------------------
// prep: Wb = [Wk|Wv] (256x128) in MFMA B-frag layout (bf16); transpose GRU
// weights; init g from slots_mu. grid 280 x 256.
// ---------------------------------------------------------------------------
__global__ __launch_bounds__(256) void prep_kernel(
    const float* __restrict__ Wk, const float* __restrict__ Wv,
    const float* __restrict__ Wih, const float* __restrict__ Whh,
    const float* __restrict__ slots, bf16_t* __restrict__ Wb,
    float* __restrict__ WihT, float* __restrict__ WhhT, float* __restrict__ g) {
  int i = blockIdx.x * 256 + threadIdx.x;
  if (i < 32768) {
    int j = i & 7, l = (i >> 3) & 63, t = (i >> 9) & 7, kb = i >> 12;
    int k = kb * 32 + (l >> 4) * 8 + j;
    int n = t * 16 + (l & 15);
    float v = (n < 64) ? Wk[k * 64 + n] : Wv[k * 64 + (n - 64)];
    Wb[i] = (bf16_t)v;
  } else if (i < 45056) {
    int idx = i - 32768;
    int c = idx / 192, j = idx % 192;
    WihT[idx] = Wih[j * 64 + c];
  } else if (i < 57344) {
    int idx = i - 45056;
    int c = idx / 192, j = idx % 192;
    WhhT[idx] = Whh[j * 64 + c];
  } else if (i < 71680) {
    int idx = i - 57344;
    g[idx] = slots[idx];
  }
}

// ---------------------------------------------------------------------------
// proj_ln v2: 512 threads (8 waves), 128-row tile, 64 KB LDS -> 2 blocks/CU =
// 4 waves/SIMD. Phase 1: 4 rows/iter per wave (16 lanes/row, lane owns 16
// consecutive cols -> 4 independent float4 loads, 8 shfls). Phase 2: wave owns
// one 16-row m-tile, 8 MFMA per kb. LDS swizzle: unit = r*32 + ((c>>3)^(r&31)).
// ---------------------------------------------------------------------------
__global__ __launch_bounds__(512) void proj_ln_kernel(
    const float* __restrict__ inp, const float* __restrict__ lng,
    const float* __restrict__ lnb, const bf16_t* __restrict__ Wb,
    bf16_t* __restrict__ kbuf, bf16_t* __restrict__ vbuf) {
  __shared__ bf16_t xs[128 * 256];  // 64 KB
  const int tid = threadIdx.x, w = tid >> 6, lane = tid & 63;
  const int q4 = lane >> 4, lp = lane & 15;
  const long row0 = (long)blockIdx.x * 128;

  float4 gv[4], bv[4];
#pragma unroll
  for (int j = 0; j < 4; ++j) {
    gv[j] = *(const float4*)(lng + lp * 16 + j * 4);
    bv[j] = *(const float4*)(lnb + lp * 16 + j * 4);
  }

  // Phase 1: wave w -> rows w*16 .. w*16+15
#pragma unroll
  for (int i = 0; i < 4; ++i) {
    int r = w * 16 + i * 4 + q4;
    const float* rp = inp + (row0 + r) * C_ + lp * 16;
    float4 x0 = *(const float4*)(rp);
    float4 x1 = *(const float4*)(rp + 4);
    float4 x2 = *(const float4*)(rp + 8);
    float4 x3 = *(const float4*)(rp + 12);
    float s = (x0.x + x0.y + x0.z + x0.w) + (x1.x + x1.y + x1.z + x1.w) +
              (x2.x + x2.y + x2.z + x2.w) + (x3.x + x3.y + x3.z + x3.w);
    float s2 = (x0.x * x0.x + x0.y * x0.y + x0.z * x0.z + x0.w * x0.w) +
               (x1.x * x1.x + x1.y * x1.y + x1.z * x1.z + x1.w * x1.w) +
               (x2.x * x2.x + x2.y * x2.y + x2.z * x2.z + x2.w * x2.w) +
               (x3.x * x3.x + x3.y * x3.y + x3.z * x3.z + x3.w * x3.w);
#pragma unroll
    for (int o = 1; o < 16; o <<= 1) {
      s += __shfl_xor(s, o);
      s2 += __shfl_xor(s2, o);
    }
    float mean = s * (1.0f / 256.0f);
    float var = s2 * (1.0f / 256.0f) - mean * mean;
    float rstd = rsqrtf(var + 1e-5f);
    bf16x8 y0, y1;
    y0[0] = (bf16_t)((x0.x - mean) * rstd * gv[0].x + bv[0].x);
    y0[1] = (bf16_t)((x0.y - mean) * rstd * gv[0].y + bv[0].y);
    y0[2] = (bf16_t)((x0.z - mean) * rstd * gv[0].z + bv[0].z);
    y0[3] = (bf16_t)((x0.w - mean) * rstd * gv[0].w + bv[0].w);
    y0[4] = (bf16_t)((x1.x - mean) * rstd * gv[1].x + bv[1].x);
    y0[5] = (bf16_t)((x1.y - mean) * rstd * gv[1].y + bv[1].y);
    y0[6] = (bf16_t)((x1.z - mean) * rstd * gv[1].z + bv[1].z);
    y0[7] = (bf16_t)((x1.w - mean) * rstd * gv[1].w + bv[1].w);
    y1[0] = (bf16_t)((x2.x - mean) * rstd * gv[2].x + bv[2].x);
    y1[1] = (bf16_t)((x2.y - mean) * rstd * gv[2].y + bv[2].y);
    y1[2] = (bf16_t)((x2.z - mean) * rstd * gv[2].z + bv[2].z);
    y1[3] = (bf16_t)((x2.w - mean) * rstd * gv[2].w + bv[2].w);
    y1[4] = (bf16_t)((x3.x - mean) * rstd * gv[3].x + bv[3].x);
    y1[5] = (bf16_t)((x3.y - mean) * rstd * gv[3].y + bv[3].y);
    y1[6] = (bf16_t)((x3.z - mean) * rstd * gv[3].z + bv[3].z);
    y1[7] = (bf16_t)((x3.w - mean) * rstd * gv[3].w + bv[3].w);
    int base = r * 32, swz = r & 31;
    *(bf16x8*)(xs + (size_t)(base + ((2 * lp) ^ swz)) * 8) = y0;
    *(bf16x8*)(xs + (size_t)(base + ((2 * lp + 1) ^ swz)) * 8) = y1;
  }
  __syncthreads();

  // Phase 2: wave w -> 16-row m-tile rows w*16..+15
  f32x4 acc[8];
  const f32x4 zf = {0.0f, 0.0f, 0.0f, 0.0f};
#pragma unroll
  for (int t = 0; t < 8; ++t) acc[t] = zf;

  const int r0 = w * 16 + lp;
  const int rsw = r0 & 31;
  for (int kb = 0; kb < 8; ++kb) {
    bf16x8 a = *(const bf16x8*)(xs + (size_t)(r0 * 32 + ((kb * 4 + q4) ^ rsw)) * 8);
#pragma unroll
    for (int t = 0; t < 8; ++t) {
      bf16x8 bfr = *(const bf16x8*)(Wb + (size_t)((kb * 8 + t) * 64 + lane) * 8);
      acc[t] = __builtin_amdgcn_mfma_f32_16x16x32_bf16(a, bfr, acc[t], 0, 0, 0);
    }
  }

  // Epilogue: D mapping col = lane&15, row = (lane>>4)*4 + reg
#pragma unroll
  for (int t = 0; t < 8; ++t) {
    bf16_t* dst = (t < 4) ? kbuf : vbuf;
    int c = (t & 3) * 16 + lp;
#pragma unroll
    for (int reg = 0; reg < 4; ++reg) {
      long gr = row0 + w * 16 + q4 * 4 + reg;
      dst[gr * 64 + c] = (bf16_t)acc[t][reg];
    }
  }
}

// ---------------------------------------------------------------------------
// qk: q[b,m] = LN(g[b,m]) @ (m<6 ? Wq : bWq); zero acc/wsum. grid 224 x 64.
// Used once before iteration 0 (later iterations fuse this into update).
// ---------------------------------------------------------------------------
__global__ __launch_bounds__(64) void qk_kernel(
    const float* __restrict__ g, const float* __restrict__ qg,
    const float* __restrict__ qb, const float* __restrict__ Wq,
    const float* __restrict__ bqg, const float* __restrict__ bqb,
    const float* __restrict__ bWq, float* __restrict__ q,
    float* __restrict__ acc, float* __restrict__ wsum) {
  __shared__ float sx[64];
  int bid = blockIdx.x, lane = threadIdx.x;
  int m = bid % 7;
  const float* lng = (m < 6) ? qg : bqg;
  const float* lnb = (m < 6) ? qb : bqb;
  const float* W = (m < 6) ? Wq : bWq;
  float gvv = g[bid * 64 + lane];
  float s = wave_sum64(gvv);
  float s2 = wave_sum64(gvv * gvv);
  float mean = s * (1.0f / 64.0f);
  float var = s2 * (1.0f / 64.0f) - mean * mean;
  float rstd = rsqrtf(var + 1e-5f);
  sx[lane] = (gvv - mean) * rstd * lng[lane] + lnb[lane];
  __syncthreads();
  float qd = 0.0f;
#pragma unroll 8
  for (int c = 0; c < 64; ++c) qd += sx[c] * W[c * 64 + lane];
  q[bid * 64 + lane] = qd;
  acc[bid * 64 + lane] = 0.0f;
  if (lane == 0) wsum[bid] = 0.0f;
}

// ---------------------------------------------------------------------------
// attend: per row: 7 logits -> softmax + EPS -> accumulate attn*v, attn.
// 4 rows/wave-iter (16-lane groups); q hoisted into registers.
// grid 1024 x 256 (one b per block, 512 rows).
// ---------------------------------------------------------------------------
__global__ __launch_bounds__(256) void attend_kernel(
    const bf16_t* __restrict__ kbuf, const bf16_t* __restrict__ vbuf,
    const float* __restrict__ q, float* __restrict__ acc,
    float* __restrict__ wsum) {
  __shared__ float qs[448];
  __shared__ float s_acc[448];
  __shared__ float s_w[7];
  int tid = threadIdx.x, w = tid >> 6, lane = tid & 63;
  int g4 = lane >> 4, lp = lane & 15;
  long chunk0 = (long)blockIdx.x * 512;
  int b = (int)(chunk0 >> 14);

  for (int idx = tid; idx < 448; idx += 256) {
    qs[idx] = q[b * 448 + idx];
    s_acc[idx] = 0.0f;
  }
  if (tid < 7) s_w[tid] = 0.0f;
  __syncthreads();

  // hoist q fragments out of the K-loop
  float4 qv[7];
  const float4* qs4 = (const float4*)qs;
#pragma unroll
  for (int m = 0; m < 7; ++m) qv[m] = qs4[m * 16 + lp];

  float av[7][4];
  float wa[7];
#pragma unroll
  for (int m = 0; m < 7; ++m) {
    wa[m] = 0.0f;
#pragma unroll
    for (int j = 0; j < 4; ++j) av[m][j] = 0.0f;
  }

  for (int it = 0; it < 32; ++it) {
    long row = chunk0 + it * 16 + w * 4 + g4;
    bf16x4 kv = *(const bf16x4*)(kbuf + row * 64 + lp * 4);
    bf16x4 vv = *(const bf16x4*)(vbuf + row * 64 + lp * 4);
    float k0 = kv[0], k1 = kv[1], k2 = kv[2], k3 = kv[3];
    float lg[7];
#pragma unroll
    for (int m = 0; m < 7; ++m)
      lg[m] = k0 * qv[m].x + k1 * qv[m].y + k2 * qv[m].z + k3 * qv[m].w;
#pragma unroll
    for (int m = 0; m < 7; ++m) {
      lg[m] += __shfl_xor(lg[m], 1);
      lg[m] += __shfl_xor(lg[m], 2);
      lg[m] += __shfl_xor(lg[m], 4);
      lg[m] += __shfl_xor(lg[m], 8);
    }
    float mx = -1e30f;
#pragma unroll
    for (int m = 0; m < 7; ++m) {
      lg[m] *= 0.125f;
      mx = fmaxf(mx, lg[m]);
    }
    float e[7], s = 0.0f;
#pragma unroll
    for (int m = 0; m < 7; ++m) {
      e[m] = __expf(lg[m] - mx);
      s += e[m];
    }
    float inv = 1.0f / s;
    float v0 = vv[0], v1 = vv[1], v2 = vv[2], v3 = vv[3];
#pragma unroll
    for (int m = 0; m < 7; ++m) {
      float a = e[m] * inv + 1e-6f;
      wa[m] += a;
      av[m][0] += a * v0;
      av[m][1] += a * v1;
      av[m][2] += a * v2;
      av[m][3] += a * v3;
    }
  }

#pragma unroll
  for (int m = 0; m < 7; ++m) {
#pragma unroll
    for (int j = 0; j < 4; ++j) {
      av[m][j] += __shfl_xor(av[m][j], 16);
      av[m][j] += __shfl_xor(av[m][j], 32);
    }
    wa[m] += __shfl_xor(wa[m], 16);
    wa[m] += __shfl_xor(wa[m], 32);
  }
  if (g4 == 0) {
#pragma unroll
    for (int m = 0; m < 7; ++m)
#pragma unroll
      for (int j = 0; j < 4; ++j) atomicAdd(&s_acc[m * 64 + lp * 4 + j], av[m][j]);
  }
  if (lane == 0) {
#pragma unroll
    for (int m = 0; m < 7; ++m) atomicAdd(&s_w[m], wa[m]);
  }
  __syncthreads();
  for (int idx = tid; idx < 448; idx += 256) atomicAdd(&acc[b * 448 + idx], s_acc[idx]);
  if (tid < 7) atomicAdd(&wsum[b * 7 + tid], s_w[tid]);
}

// ---------------------------------------------------------------------------
// update: fu = acc/wsum -> GRU -> +MLP residual -> gout; if write_q, also
// compute next-iteration q = LN(gout) @ Wq/bWq and zero acc/wsum.
// grid 224 x 192.
// ---------------------------------------------------------------------------
__global__ __launch_bounds__(192) void update_kernel(
    const float* __restrict__ acc, const float* __restrict__ wsum,
    const float* __restrict__ g, const float* __restrict__ WihT,
    const float* __restrict__ WhhT, const float* __restrict__ bih,
    const float* __restrict__ bhh, const float* __restrict__ mlg,
    const float* __restrict__ mlb, const float* __restrict__ mW1,
    const float* __restrict__ mb1, const float* __restrict__ mW2,
    const float* __restrict__ mb2, const float* __restrict__ bmlg,
    const float* __restrict__ bmlb, const float* __restrict__ bW1,
    const float* __restrict__ bb1, const float* __restrict__ bW2,
    const float* __restrict__ bb2, float* __restrict__ gout,
    const float* __restrict__ qg, const float* __restrict__ qb,
    const float* __restrict__ Wq, const float* __restrict__ bqg,
    const float* __restrict__ bqb, const float* __restrict__ bWq,
    float* __restrict__ qout, float* __restrict__ accz,
    float* __restrict__ wsz, int write_q) {
  __shared__ float fu[64], hp[64], gi[192], gh[192], h2[64], xb[64], a1[128], go[64];
  int tid = threadIdx.x, bid = blockIdx.x, m = bid % 7;

  const float *lg_, *lb_, *W1_, *b1_, *W2_, *b2_;
  if (m < 6) { lg_ = mlg; lb_ = mlb; W1_ = mW1; b1_ = mb1; W2_ = mW2; b2_ = mb2; }
  else       { lg_ = bmlg; lb_ = bmlb; W1_ = bW1; b1_ = bb1; W2_ = bW2; b2_ = bb2; }

  if (tid < 64) {
    float wv = wsum[bid];
    fu[tid] = acc[bid * 64 + tid] / wv;
    hp[tid] = g[bid * 64 + tid];
  }
  __syncthreads();

  {
    int j = tid;
    float a = bih[j], bsum = bhh[j];
    for (int c = 0; c < 64; ++c) {
      a += fu[c] * WihT[c * 192 + j];
      bsum += hp[c] * WhhT[c * 192 + j];
    }
    gi[j] = a;
    gh[j] = bsum;
  }
  __syncthreads();

  if (tid < 64) {
    int d = tid;
    float r = sigmoidf_(gi[d] + gh[d]);
    float z = sigmoidf_(gi[64 + d] + gh[64 + d]);
    float n = tanhf_(gi[128 + d] + r * gh[128 + d]);
    float h = (1.0f - z) * n + z * hp[d];
    h2[d] = h;
    float s = wave_sum64(h);
    float s2 = wave_sum64(h * h);
    float mean = s * (1.0f / 64.0f);
    float var = s2 * (1.0f / 64.0f) - mean * mean;
    xb[d] = (h - mean) * rsqrtf(var + 1e-5f) * lg_[d] + lb_[d];
  }
  __syncthreads();

  if (tid < 128) {
    int hh = tid;
    float a = b1_[hh];
    for (int c = 0; c < 64; ++c) a += xb[c] * W1_[c * 128 + hh];
    a1[hh] = fmaxf(a, 0.0f);
  }
  __syncthreads();

  if (tid < 64) {
    int d = tid;
    float o = b2_[d];
    for (int hh = 0; hh < 128; ++hh) o += a1[hh] * W2_[hh * 64 + d];
    float res = h2[d] + o;
    gout[bid * 64 + d] = res;
    go[d] = res;
  }
  __syncthreads();

  if (write_q) {
    if (tid < 64) {
      const float* qlng = (m < 6) ? qg : bqg;
      const float* qlnb = (m < 6) ? qb : bqb;
      const float* W = (m < 6) ? Wq : bWq;
      float gvv = go[tid];
      float s = wave_sum64(gvv);
      float s2 = wave_sum64(gvv * gvv);
      float mean = s * (1.0f / 64.0f);
      float var = s2 * (1.0f / 64.0f) - mean * mean;
      xb[tid] = (gvv - mean) * rsqrtf(var + 1e-5f) * qlng[tid] + qlnb[tid];
      __syncwarp();
      float qd = 0.0f;
      const float* Wl = W;
#pragma unroll 8
      for (int c = 0; c < 64; ++c) qd += xb[c] * Wl[c * 64 + tid];
      qout[bid * 64 + tid] = qd;
      accz[bid * 64 + tid] = 0.0f;
      if (tid == 0) wsz[bid] = 0.0f;
    }
  }
}

// ---------------------------------------------------------------------------
extern "C" void kernel_launch(void* const* d_in, const int* in_sizes, int n_in,
                              void* d_out, int out_size, void* d_ws, size_t ws_size,
                              hipStream_t stream) {
  const float* inputs   = (const float*)d_in[0];
  const float* slots_mu = (const float*)d_in[1];
  const float* ln_in_g  = (const float*)d_in[2];
  const float* ln_in_b  = (const float*)d_in[3];
  const float* Wk       = (const float*)d_in[4];
  const float* Wv       = (const float*)d_in[5];
  const float* q_ln_g   = (const float*)d_in[6];
  const float* q_ln_b   = (const float*)d_in[7];
  const float* Wq       = (const float*)d_in[8];
  const float* bq_ln_g  = (const float*)d_in[9];
  const float* bq_ln_b  = (const float*)d_in[10];
  const float* bWq      = (const float*)d_in[11];
  const float* gru_Wih  = (const float*)d_in[12];
  const float* gru_Whh  = (const float*)d_in[13];
  const float* gru_bih  = (const float*)d_in[14];
  const float* gru_bhh  = (const float*)d_in[15];
  const float* mlp_ln_g = (const float*)d_in[16];
  const float* mlp_ln_b = (const float*)d_in[17];
  const float* mlp_W1   = (const float*)d_in[18];
  const float* mlp_b1   = (const float*)d_in[19];
  const float* mlp_W2   = (const float*)d_in[20];
  const float* mlp_b2   = (const float*)d_in[21];
  const float* bmlp_ln_g = (const float*)d_in[22];
  const float* bmlp_ln_b = (const float*)d_in[23];
  const float* bmlp_W1  = (const float*)d_in[24];
  const float* bmlp_b1  = (const float*)d_in[25];
  const float* bmlp_W2  = (const float*)d_in[26];
  const float* bmlp_b2  = (const float*)d_in[27];
  float* out = (float*)d_out;

  char* ws = (char*)d_ws;
  const size_t KV_BYTES = (size_t)ROWS_TOTAL * 64 * 2;
  bf16_t* kbuf = (bf16_t*)ws;
  bf16_t* vbuf = (bf16_t*)(ws + KV_BYTES);
  bf16_t* Wb   = (bf16_t*)(ws + 2 * KV_BYTES);
  float* WihT  = (float*)(ws + 2 * KV_BYTES + 65536);
  float* WhhT  = (float*)(ws + 2 * KV_BYTES + 65536 + 49152);
  float* gbuf  = (float*)(ws + 2 * KV_BYTES + 65536 + 2 * 49152);
  float* qbuf  = (float*)(ws + 2 * KV_BYTES + 65536 + 2 * 49152 + 57344);
  float* accb  = (float*)(ws + 2 * KV_BYTES + 65536 + 2 * 49152 + 2 * 57344);
  float* wsumb = (float*)(ws + 2 * KV_BYTES + 65536 + 2 * 49152 + 3 * 57344);

  prep_kernel<<<280, 256, 0, stream>>>(Wk, Wv, gru_Wih, gru_Whh, slots_mu, Wb,
                                       WihT, WhhT, gbuf);
  proj_ln_kernel<<<ROWS_TOTAL / 128, 512, 0, stream>>>(inputs, ln_in_g, ln_in_b,
                                                       Wb, kbuf, vbuf);
  qk_kernel<<<224, 64, 0, stream>>>(gbuf, q_ln_g, q_ln_b, Wq, bq_ln_g, bq_ln_b,
                                    bWq, qbuf, accb, wsumb);
  for (int it = 0; it < 3; ++it) {
    attend_kernel<<<ROWS_TOTAL / 512, 256, 0, stream>>>(kbuf, vbuf, qbuf, accb,
                                                        wsumb);
    update_kernel<<<224, 192, 0, stream>>>(
        accb, wsumb, gbuf, WihT, WhhT, gru_bih, gru_bhh, mlp_ln_g, mlp_ln_b,
        mlp_W1, mlp_b1, mlp_W2, mlp_b2, bmlp_ln_g, bmlp_ln_b, bmlp_W1, bmlp_b1,
        bmlp_W2, bmlp_b2, (it == 2) ? out : gbuf, q_ln_g, q_ln_b, Wq, bq_ln_g,
        bq_ln_b, bWq, qbuf, accb, wsumb, (it < 2) ? 1 : 0);
  }
}